// Round 16
// baseline (12065.520 us; speedup 1.0000x reference)
//
#include <hip/hip_runtime.h>
#include <hip/hip_bf16.h>

#define B_ 64
#define T_ 1024
#define E_ 256
#define H_ 512
#define ZN_ 2048
#define NSLICE 64    // persistent workgroups; each owns 8 hidden cols (32 z-cols)
#define KTX 8        // x-part K tiles of 32 (E=256)
#define KTH 16       // h-part K tiles of 32 (H=512)
#define KT_ (KTX + KTH)

typedef short bf16x8 __attribute__((ext_vector_type(8)));
typedef float f32x4 __attribute__((ext_vector_type(4)));
typedef int i32x4 __attribute__((ext_vector_type(4)));

union frag_u { i32x4 i; bf16x8 h; };

#define RAW_BAR() __builtin_amdgcn_s_barrier()
#define LGKM0() asm volatile("s_waitcnt lgkmcnt(0)" ::: "memory")
#define VM0() asm volatile("s_waitcnt vmcnt(0)" ::: "memory")
#define SCHED_BAR() __builtin_amdgcn_sched_barrier(0)

__device__ __forceinline__ short f2bf(float f) {
  union { float f; unsigned u; } v; v.f = f;
  unsigned r = v.u + 0x7fffu + ((v.u >> 16) & 1u);
  return (short)(r >> 16);
}
__device__ __forceinline__ float sigmoidf_(float x) { return 1.f / (1.f + __expf(-x)); }
__device__ __forceinline__ float tanhf_(float x) {
  x = fminf(10.f, fmaxf(-10.f, x));
  float e = __expf(2.f * x);
  return (e - 1.f) / (e + 1.f);
}

// system-scope (coherent point) ops
__device__ __forceinline__ i32x4 ld_sys(const void* p) {
  i32x4 r;
  asm volatile("global_load_dwordx4 %0, %1, off sc0 sc1" : "=v"(r) : "v"(p) : "memory");
  return r;
}
__device__ __forceinline__ void st_sys(void* p, i32x4 v) {
  asm volatile("global_store_dwordx4 %0, %1, off sc0 sc1" :: "v"(p), "v"(v) : "memory");
}

// ---------------- phase 0: one-time prep ----------------

__global__ void k_emb_cvt(const float* __restrict__ emb, short* __restrict__ dst, int n8) {
  int i = blockIdx.x * blockDim.x + threadIdx.x;
  if (i >= n8) return;
  const float4* s = (const float4*)emb;
  float4 a = s[2 * i], b = s[2 * i + 1];
  bf16x8 o;
  o[0] = f2bf(a.x); o[1] = f2bf(a.y); o[2] = f2bf(a.z); o[3] = f2bf(a.w);
  o[4] = f2bf(b.x); o[5] = f2bf(b.y); o[6] = f2bf(b.z); o[7] = f2bf(b.w);
  ((bf16x8*)dst)[i] = o;
}

// B-fragment table: wf[((s*2+nt)*KT_+kt)*64 + lane], k = kt*32 + (lane>>4)*8 + i,
// zcol = g*H + s*8 + nt*4 + hc with c16 = lane&15, g = c16&3, hc = c16>>2.
__global__ void k_wfrag(const float* __restrict__ Wx, const float* __restrict__ Wh,
                        short* __restrict__ wf) {
  int tid = blockIdx.x * blockDim.x + threadIdx.x;
  if (tid >= NSLICE * 2 * KT_ * 64) return;
  int lane = tid & 63;
  int kt = (tid >> 6) % KT_;
  int nt = (tid >> 6) / KT_ % 2;
  int s = tid / (64 * KT_ * 2);
  int c16 = lane & 15, ksub = lane >> 4;
  int g = c16 & 3, hc = c16 >> 2;
  int zcol = g * H_ + s * 8 + nt * 4 + hc;
  int k0 = kt * 32 + ksub * 8;
  bf16x8 o;
#pragma unroll
  for (int i = 0; i < 8; ++i) {
    int k = k0 + i;
    float v = (k < E_) ? Wx[(size_t)k * ZN_ + zcol] : Wh[(size_t)(k - E_) * ZN_ + zcol];
    o[i] = f2bf(v);
  }
  ((bf16x8*)wf)[tid] = o;
}

// tokens transposed (u16) + per-step batch mask
__global__ void k_tok(const int* __restrict__ tok, unsigned short* __restrict__ tokT,
                      unsigned long long* __restrict__ mask) {
  int t = blockIdx.x * blockDim.x + threadIdx.x;
  if (t >= T_) return;
  unsigned long long m = 0ull;
  for (int b = 0; b < B_; ++b) {
    int tk = tok[b * T_ + t];
    tokT[t * B_ + b] = (unsigned short)tk;
    if (tk != 0) m |= (1ull << b);
  }
  mask[t] = m;
}

// granule mailbox init: hx[par][row 0..63][cg 0..127] of 16B {2bf16,2bf16,epoch,0}.
// par0 = h0 with epoch 0; par1 = zeros (epoch 0).
__global__ void k_init(const float* __restrict__ h0, int* __restrict__ hx) {
  int i = blockIdx.x * blockDim.x + threadIdx.x;
  if (i >= 2 * B_ * 128) return;
  int par = i >> 13;
  int row = (i >> 7) & 63;
  int cg = i & 127;
  i32x4 g = {0, 0, 0, 0};
  if (par == 0) {
    const float* src = h0 + row * H_ + cg * 4;
    g[0] = ((int)f2bf(src[0]) & 0xffff) | ((int)f2bf(src[1]) << 16);
    g[1] = ((int)f2bf(src[2]) & 0xffff) | ((int)f2bf(src[3]) << 16);
  }
  ((i32x4*)hx)[i] = g;
}

// ---------------- persistent LSTM kernel ----------------
// 64 blocks x 384 threads (6 waves). No block barrier, no tag array, no producer ack.
//   waves 0-3: compute; poll = batched granule loads (epoch embedded in data, 16B atomic)
//   waves 4-5: out stores from parity LDS staging (LDS spin only)
// Publish at step t: epoch t+1 granules into buffer (t+1)&1, fire-and-forget.

__global__ __launch_bounds__(384, 2) void k_lstm(
    const unsigned short* __restrict__ tokT, const short* __restrict__ emb,
    const short* __restrict__ wf, const float* __restrict__ bias,
    const unsigned long long* __restrict__ maskv,
    int* __restrict__ hx,
    const float* __restrict__ h0, const float* __restrict__ c0,
    float* __restrict__ out)
{
  __shared__ __align__(16) short x_wf[2 * KTX * 64 * 8];   // 16 KB Wx fragments
  __shared__ __align__(16) short wh_lds[2 * KTH * 64 * 8]; // 32 KB Wh fragments
  __shared__ __align__(16) float hlocF[2][B_][8];          // 4 KB out staging (parity)
  __shared__ __align__(16) short hlocBF[B_][8];            // 1 KB publish staging
  __shared__ int scnt, ocnt;

  int s = blockIdx.x;
  int w = threadIdx.x >> 6, l = threadIdx.x & 63;
  int c16 = l & 15, ksub = l >> 4;
  int g = c16 & 3, hc = c16 >> 2;
  int base = l & ~3;
  int arow = w * 16 + c16;                // compute waves: A-fragment row

  if (threadIdx.x == 0) { scnt = 0; ocnt = 0; }

  // --- Wx fragments -> LDS ---
  for (int idx = threadIdx.x; idx < 2 * KTX * 64; idx += 384) {
    int lane = idx & 63;
    int ktn = idx >> 6;
    int nt = ktn / KTX, kt = ktn % KTX;
    ((bf16x8*)x_wf)[idx] = ((const bf16x8*)wf)[(((size_t)(s * 2 + nt)) * KT_ + kt) * 64 + lane];
  }
  // --- Wh fragments -> LDS ---
  for (int idx = threadIdx.x; idx < 2 * KTH * 64; idx += 384) {
    int lane = idx & 63;
    int ktn = idx >> 6;
    int nt = ktn / KTH, kt = ktn % KTH;
    ((bf16x8*)wh_lds)[idx] = ((const bf16x8*)wf)[(((size_t)(s * 2 + nt)) * KT_ + KTX + kt) * 64 + lane];
  }

  // --- compute-wave state ---
  float zb0 = 0.f, zb1 = 0.f;
  float cst[2][4], hst[2][4];
  if (w < 4) {
    zb0 = bias[g * H_ + s * 8 + 0 + hc];
    zb1 = bias[g * H_ + s * 8 + 4 + hc];
#pragma unroll
    for (int j = 0; j < 2; ++j) {
      int col = s * 8 + j * 4 + hc;
#pragma unroll
      for (int r = 0; r < 4; ++r) {
        int row = w * 16 + ksub * 4 + r;
        cst[j][r] = c0[row * H_ + col];
        hst[j][r] = h0[row * H_ + col];
      }
    }
  }
  LGKM0();
  RAW_BAR();   // LDS weights + counters ready (one-time)

  // x-part of z for step t (A: emb gather, B: LDS fragments)
  f32x4 accx0 = {0.f, 0.f, 0.f, 0.f}, accx1 = {0.f, 0.f, 0.f, 0.f};
  auto compute_x = [&](int t) {
    int tk = tokT[t * B_ + arow];
    const bf16x8* ax = (const bf16x8*)emb + (size_t)tk * 32 + ksub;
    f32x4 a0 = {0.f, 0.f, 0.f, 0.f}, a1 = {0.f, 0.f, 0.f, 0.f};
#pragma unroll
    for (int kt = 0; kt < KTX; ++kt) {
      bf16x8 a = ax[kt * 4];
      a0 = __builtin_amdgcn_mfma_f32_16x16x32_bf16(a, ((const bf16x8*)x_wf)[(0 * KTX + kt) * 64 + l], a0, 0, 0, 0);
      a1 = __builtin_amdgcn_mfma_f32_16x16x32_bf16(a, ((const bf16x8*)x_wf)[(1 * KTX + kt) * 64 + l], a1, 0, 0, 0);
    }
    accx0 = a0; accx1 = a1;
  };

  if (w < 4) compute_x(0);

  if (w < 4) {
    // ================= compute waves =================
    const bf16x8* whp = (const bf16x8*)wh_lds;
    for (int t = 0; t < T_; ++t) {
      int par = t & 1;

      // --- poll+load: batched granule loads; epoch rides in the data (16B atomic) ---
      // lane needs row arow, cols {ksub*8 + kt*32 .. +8} => granules kt*8+ksub*2, +1
      const i32x4* gbase = (const i32x4*)hx + ((size_t)par * B_ + arow) * 128 + ksub * 2;
      frag_u hf[KTH];
      for (;;) {
        i32x4 ga[KTH], gb[KTH];
#pragma unroll
        for (int kt = 0; kt < KTH; ++kt) {
          ga[kt] = ld_sys(gbase + kt * 8);
          gb[kt] = ld_sys(gbase + kt * 8 + 1);
        }
        VM0();
        SCHED_BAR();
        bool ok = true;
#pragma unroll
        for (int kt = 0; kt < KTH; ++kt)
          ok = ok && ga[kt][2] >= t && gb[kt][2] >= t;
        if (__all(ok)) {
#pragma unroll
          for (int kt = 0; kt < KTH; ++kt) {
            i32x4 f = {ga[kt][0], ga[kt][1], gb[kt][0], gb[kt][1]};
            hf[kt].i = f;
          }
          break;
        }
      }

      // --- z = accx + h_t @ Wh (2 n-tiles x 16 MFMAs, B from LDS) ---
      f32x4 ac0 = accx0, ac1 = accx1;
#pragma unroll
      for (int kt = 0; kt < KTH; ++kt) {
        ac0 = __builtin_amdgcn_mfma_f32_16x16x32_bf16(hf[kt].h, whp[(0 * KTH + kt) * 64 + l], ac0, 0, 0, 0);
        ac1 = __builtin_amdgcn_mfma_f32_16x16x32_bf16(hf[kt].h, whp[(1 * KTH + kt) * 64 + l], ac1, 0, 0, 0);
      }

      // --- staging reuse guard: out waves consumed step t-2 (LDS spin, fast) ---
      while (__hip_atomic_load(&ocnt, __ATOMIC_ACQUIRE, __HIP_MEMORY_SCOPE_WORKGROUP) < 2 * (t - 1)) {}

      // --- gates + state update (owner lanes g==0) ---
      unsigned long long mk = maskv[t];
#pragma unroll
      for (int j = 0; j < 2; ++j) {
        float zb = (j == 0) ? zb0 : zb1;
        int lc = j * 4 + hc;
        float act[4];
#pragma unroll
        for (int r = 0; r < 4; ++r) {
          float z = ((j == 0) ? ac0[r] : ac1[r]) + zb;
          act[r] = (g == 2) ? tanhf_(z) : sigmoidf_(z);
        }
#pragma unroll
        for (int r = 0; r < 4; ++r) {
          float fs = __shfl(act[r], base + 1);   // sigmoid(z_f)
          float gt = __shfl(act[r], base + 2);   // tanh(z_g)
          float os = __shfl(act[r], base + 3);   // sigmoid(z_o)
          if (g == 0) {                          // act[r] = sigmoid(z_i)
            int row = w * 16 + ksub * 4 + r;
            bool mm = (mk >> row) & 1ull;
            float cn = fs * cst[j][r] + act[r] * gt;
            float hn = os * tanhf_(cn);
            if (mm) { cst[j][r] = cn; hst[j][r] = hn; }
            hlocF[par][row][lc] = hst[j][r];
            hlocBF[row][lc] = f2bf(hst[j][r]);
          }
        }
      }
      LGKM0();        // wave-private slab writes drained
      SCHED_BAR();

      if (l == 0)
        __hip_atomic_fetch_add(&scnt, 1, __ATOMIC_RELEASE, __HIP_MEMORY_SCOPE_WORKGROUP);

      // --- publish: fire-and-forget epoch-carrying granules (no VM0, no tag) ---
      if (t + 1 < T_) {
        if (l < 16) {
          int row = w * 16 + l;
          int ep = t + 1;
          int d0 = *(const int*)&hlocBF[row][0];
          int d1 = *(const int*)&hlocBF[row][2];
          int d2 = *(const int*)&hlocBF[row][4];
          int d3 = *(const int*)&hlocBF[row][6];
          i32x4 g0 = {d0, d1, ep, 0};
          i32x4 g1 = {d2, d3, ep, 0};
          i32x4* gp = (i32x4*)hx + ((size_t)(1 - par) * B_ + row) * 128 + s * 2;
          st_sys(gp, g0);
          st_sys(gp + 1, g1);
        }
        compute_x(t + 1);   // overlaps granule propagation
      } else if (g == 0) {
        // final h_T / c_T
#pragma unroll
        for (int j = 0; j < 2; ++j) {
          int col = s * 8 + j * 4 + hc;
#pragma unroll
          for (int r = 0; r < 4; ++r) {
            int row = w * 16 + ksub * 4 + r;
            out[(size_t)B_ * T_ * H_ + row * H_ + col] = hst[j][r];
            out[(size_t)B_ * T_ * H_ + B_ * H_ + row * H_ + col] = cst[j][r];
          }
        }
      }
    }
  } else {
    // ================= out waves (w=4,5) =================
    for (int t = 0; t < T_; ++t) {
      int par = t & 1;
      while (__hip_atomic_load(&scnt, __ATOMIC_ACQUIRE, __HIP_MEMORY_SCOPE_WORKGROUP) < 4 * (t + 1)) {}
      int row = (w - 4) * 32 + (l >> 1), half = l & 1;
      f32x4 v = *(const f32x4*)&hlocF[par][row][half * 4];
      LGKM0();
      if (l == 0)
        __hip_atomic_fetch_add(&ocnt, 1, __ATOMIC_RELEASE, __HIP_MEMORY_SCOPE_WORKGROUP);
      __builtin_nontemporal_store(v, (f32x4*)(out + ((size_t)row * T_ + t) * H_ + s * 8 + half * 4));
    }
  }
}

// ---------------- launch ----------------

extern "C" void kernel_launch(void* const* d_in, const int* in_sizes, int n_in,
                              void* d_out, int out_size, void* d_ws, size_t ws_size,
                              hipStream_t stream) {
  (void)in_sizes; (void)n_in; (void)out_size; (void)ws_size;
  const int* tokens = (const int*)d_in[0];
  const float* h0 = (const float*)d_in[1];
  const float* c0 = (const float*)d_in[2];
  const float* emb = (const float*)d_in[3];
  const float* Wx = (const float*)d_in[4];
  const float* Wh = (const float*)d_in[5];
  const float* bias = (const float*)d_in[6];
  float* out = (float*)d_out;
  char* ws = (char*)d_ws;

  // ws layout (bytes): emb_bf16 16,384,000 | wfrag 3,145,728 | mask 8,192 |
  //                    tokT(u16) 131,072 | hx granules 262,144  (= 19,931,136)
  short* emb_bf = (short*)(ws);
  short* wf     = (short*)(ws + 16384000);
  unsigned long long* mask = (unsigned long long*)(ws + 19529728);
  unsigned short* tokT = (unsigned short*)(ws + 19537920);
  int* hx       = (int*)(ws + 19668992);

  k_emb_cvt<<<(1024000 + 255) / 256, 256, 0, stream>>>(emb, emb_bf, 1024000);
  k_wfrag<<<(NSLICE * 2 * KT_ * 64 + 255) / 256, 256, 0, stream>>>(Wx, Wh, wf);
  k_tok<<<(T_ + 255) / 256, 256, 0, stream>>>(tokens, tokT, mask);
  k_init<<<(2 * B_ * 128 + 255) / 256, 256, 0, stream>>>(h0, hx);

  k_lstm<<<NSLICE, 384, 0, stream>>>(tokT, emb_bf, wf, bias, mask,
                                     hx, h0, c0, out);
}

// Round 17
// 6279.119 us; speedup vs baseline: 1.9215x; 1.9215x over previous
//
#include <hip/hip_runtime.h>
#include <hip/hip_bf16.h>

#define B_ 64
#define T_ 1024
#define E_ 256
#define H_ 512
#define ZN_ 2048
#define NSLICE 64    // persistent workgroups; each owns 8 hidden cols (32 z-cols)
#define KTX 8        // x-part K tiles of 32 (E=256)
#define KTH 16       // h-part K tiles of 32 (H=512)
#define KT_ (KTX + KTH)

typedef short bf16x8 __attribute__((ext_vector_type(8)));
typedef float f32x4 __attribute__((ext_vector_type(4)));
typedef int i32x4 __attribute__((ext_vector_type(4)));

union frag_u { i32x4 i; bf16x8 h; };

#define RAW_BAR() __builtin_amdgcn_s_barrier()
#define LGKM0() asm volatile("s_waitcnt lgkmcnt(0)" ::: "memory")
#define VM0() asm volatile("s_waitcnt vmcnt(0)" ::: "memory")

__device__ __forceinline__ short f2bf(float f) {
  union { float f; unsigned u; } v; v.f = f;
  unsigned r = v.u + 0x7fffu + ((v.u >> 16) & 1u);
  return (short)(r >> 16);
}
__device__ __forceinline__ float sigmoidf_(float x) { return 1.f / (1.f + __expf(-x)); }
__device__ __forceinline__ float tanhf_(float x) {
  x = fminf(10.f, fmaxf(-10.f, x));
  float e = __expf(2.f * x);
  return (e - 1.f) / (e + 1.f);
}

// system-scope (coherent point / Infinity Cache) ops
__device__ __forceinline__ i32x4 ld_sys(const void* p) {
  i32x4 r;
  asm volatile("global_load_dwordx4 %0, %1, off sc0 sc1" : "=v"(r) : "v"(p) : "memory");
  return r;
}
__device__ __forceinline__ void st_sys(void* p, i32x4 v) {
  asm volatile("global_store_dwordx4 %0, %1, off sc0 sc1" :: "v"(p), "v"(v) : "memory");
}
__device__ __forceinline__ int ld_sys_poll(const int* p) {
  int r;
  asm volatile("global_load_dword %0, %1, off sc0 sc1\n\ts_waitcnt vmcnt(0)"
               : "=v"(r) : "v"(p) : "memory");
  return r;
}
__device__ __forceinline__ void st_sys_i32(int* p, int v) {
  asm volatile("global_store_dword %0, %1, off sc0 sc1" :: "v"(p), "v"(v) : "memory");
}

// ---------------- phase 0: one-time prep ----------------

__global__ void k_emb_cvt(const float* __restrict__ emb, short* __restrict__ dst, int n8) {
  int i = blockIdx.x * blockDim.x + threadIdx.x;
  if (i >= n8) return;
  const float4* s = (const float4*)emb;
  float4 a = s[2 * i], b = s[2 * i + 1];
  bf16x8 o;
  o[0] = f2bf(a.x); o[1] = f2bf(a.y); o[2] = f2bf(a.z); o[3] = f2bf(a.w);
  o[4] = f2bf(b.x); o[5] = f2bf(b.y); o[6] = f2bf(b.z); o[7] = f2bf(b.w);
  ((bf16x8*)dst)[i] = o;
}

// B-fragment table: wf[((s*2+nt)*KT_+kt)*64 + lane], k = kt*32 + (lane>>4)*8 + i,
// zcol = g*H + s*8 + nt*4 + hc with c16 = lane&15, g = c16&3, hc = c16>>2.
__global__ void k_wfrag(const float* __restrict__ Wx, const float* __restrict__ Wh,
                        short* __restrict__ wf) {
  int tid = blockIdx.x * blockDim.x + threadIdx.x;
  if (tid >= NSLICE * 2 * KT_ * 64) return;
  int lane = tid & 63;
  int kt = (tid >> 6) % KT_;
  int nt = (tid >> 6) / KT_ % 2;
  int s = tid / (64 * KT_ * 2);
  int c16 = lane & 15, ksub = lane >> 4;
  int g = c16 & 3, hc = c16 >> 2;
  int zcol = g * H_ + s * 8 + nt * 4 + hc;
  int k0 = kt * 32 + ksub * 8;
  bf16x8 o;
#pragma unroll
  for (int i = 0; i < 8; ++i) {
    int k = k0 + i;
    float v = (k < E_) ? Wx[(size_t)k * ZN_ + zcol] : Wh[(size_t)(k - E_) * ZN_ + zcol];
    o[i] = f2bf(v);
  }
  ((bf16x8*)wf)[tid] = o;
}

// tokens transposed + per-step batch mask
__global__ void k_tok(const int* __restrict__ tok, int* __restrict__ tokT,
                      unsigned long long* __restrict__ mask) {
  int t = blockIdx.x * blockDim.x + threadIdx.x;
  if (t >= T_) return;
  unsigned long long m = 0ull;
  for (int b = 0; b < B_; ++b) {
    int tk = tok[b * T_ + t];
    tokT[t * B_ + b] = tk;
    if (tk != 0) m |= (1ull << b);
  }
  mask[t] = m;
}

__global__ void k_init(const float* __restrict__ h0, short* __restrict__ hbuf0,
                       int* __restrict__ flags) {
  int i = blockIdx.x * blockDim.x + threadIdx.x;
  if (i < 1024) flags[i] = 0;                 // 64 flags x 16 ints padding
  if (i >= B_ * H_) return;
  hbuf0[i] = f2bf(h0[i]);
}

// ---------------- persistent LSTM kernel ----------------
// 64 blocks x 512 threads. Role-split waves:
//   waves 0-3: compute (wave w = rows w*16..w*16+16, cols s*8..s*8+8, 2 MFMA chains)
//   wave 4:    sync (poll flags, publish h, store flag)  -- vmcnt always clean
//   waves 5-6: out stores from LDS staging               -- never wait on vmcnt
//   wave 7:    idle (barriers only)
// Raw s_barrier everywhere (no compiler vmcnt drain).
// Poll is ADAPTIVE: lanes whose flag already reached t stop re-loading, so
// read pressure on each flag line decays as flags arrive (r16 lesson:
// same-line sc1 read storms queue at the coherent point).

__global__ __launch_bounds__(512, 2) void k_lstm(
    const int* __restrict__ tokT, const short* __restrict__ emb,
    const short* __restrict__ wf, const float* __restrict__ bias,
    const unsigned long long* __restrict__ maskv,
    short* __restrict__ hb0, short* __restrict__ hb1,
    const float* __restrict__ h0, const float* __restrict__ c0,
    float* __restrict__ out, int* __restrict__ flags)
{
  __shared__ __align__(16) short x_wf[2 * KTX * 64 * 8];  // 16 KB Wx fragments
  __shared__ __align__(16) float hlocF[B_][8];            // 2 KB f32 h staging
  __shared__ __align__(16) short hlocBF[B_][8];           // 1 KB bf16 h staging

  int s = blockIdx.x;
  int w = threadIdx.x >> 6, l = threadIdx.x & 63;
  int c16 = l & 15, ksub = l >> 4;
  int g = c16 & 3, hc = c16 >> 2;
  int base = l & ~3;
  int arow = w * 16 + c16;                // compute waves: A-fragment row

  // --- Wx fragments -> LDS (16 KB, all threads) ---
  for (int idx = threadIdx.x; idx < 2 * KTX * 64; idx += 512) {
    int lane = idx & 63;
    int ktn = idx >> 6;
    int nt = ktn / KTX, kt = ktn % KTX;
    ((bf16x8*)x_wf)[idx] = ((const bf16x8*)wf)[(((size_t)(s * 2 + nt)) * KT_ + kt) * 64 + lane];
  }

  // --- compute-wave state ---
  bf16x8 wreg0[KTH], wreg1[KTH];
  float zb0 = 0.f, zb1 = 0.f;
  float cst[2][4], hst[2][4];
  if (w < 4) {
    const bf16x8* b0 = (const bf16x8*)wf + (((size_t)(s * 2 + 0)) * KT_ + KTX) * 64 + l;
    const bf16x8* b1 = (const bf16x8*)wf + (((size_t)(s * 2 + 1)) * KT_ + KTX) * 64 + l;
#pragma unroll
    for (int kt = 0; kt < KTH; ++kt) { wreg0[kt] = b0[kt * 64]; wreg1[kt] = b1[kt * 64]; }
    zb0 = bias[g * H_ + s * 8 + 0 + hc];
    zb1 = bias[g * H_ + s * 8 + 4 + hc];
#pragma unroll
    for (int j = 0; j < 2; ++j) {
      int col = s * 8 + j * 4 + hc;
#pragma unroll
      for (int r = 0; r < 4; ++r) {
        int row = w * 16 + ksub * 4 + r;
        cst[j][r] = c0[row * H_ + col];
        hst[j][r] = h0[row * H_ + col];
      }
    }
  }
  LGKM0();
  RAW_BAR();   // x_wf ready

  // x-part of z for step t (A: emb gather, B: LDS fragments)
  f32x4 accx0 = {0.f, 0.f, 0.f, 0.f}, accx1 = {0.f, 0.f, 0.f, 0.f};
  auto compute_x = [&](int t) {
    int tk = tokT[t * B_ + arow];
    const bf16x8* ax = (const bf16x8*)emb + (size_t)tk * 32 + ksub;
    f32x4 a0 = {0.f, 0.f, 0.f, 0.f}, a1 = {0.f, 0.f, 0.f, 0.f};
#pragma unroll
    for (int kt = 0; kt < KTX; ++kt) {
      bf16x8 a = ax[kt * 4];
      a0 = __builtin_amdgcn_mfma_f32_16x16x32_bf16(a, ((const bf16x8*)x_wf)[(0 * KTX + kt) * 64 + l], a0, 0, 0, 0);
      a1 = __builtin_amdgcn_mfma_f32_16x16x32_bf16(a, ((const bf16x8*)x_wf)[(1 * KTX + kt) * 64 + l], a1, 0, 0, 0);
    }
    accx0 = a0; accx1 = a1;
  };

  if (w < 4) compute_x(0);

  for (int t = 0; t < T_; ++t) {
    const short* hr = (t & 1) ? hb1 : hb0;
    short* hw       = (t & 1) ? hb0 : hb1;

    // --- A: sync wave polls 64 block-flags; satisfied lanes stop loading ---
    if (w == 4 && t > 0) {
      int v = 0;
      for (;;) {
        if (v < t) v = ld_sys_poll(flags + l * 16);
        if (__all(v >= t)) break;
      }
    }
    RAW_BAR();   // B: h_t visible to all

    // --- C: compute waves ---
    if (w < 4) {
      const short* hbase = hr + arow * H_ + ksub * 8;
      frag_u hf[KTH];
#pragma unroll
      for (int kt = 0; kt < KTH; ++kt) hf[kt].i = ld_sys(hbase + kt * 32);
      VM0();
      __builtin_amdgcn_sched_barrier(0);

      f32x4 ac0 = accx0, ac1 = accx1;
#pragma unroll
      for (int kt = 0; kt < KTH; ++kt) {
        ac0 = __builtin_amdgcn_mfma_f32_16x16x32_bf16(hf[kt].h, wreg0[kt], ac0, 0, 0, 0);
        ac1 = __builtin_amdgcn_mfma_f32_16x16x32_bf16(hf[kt].h, wreg1[kt], ac1, 0, 0, 0);
      }

      unsigned long long mk = maskv[t];
#pragma unroll
      for (int j = 0; j < 2; ++j) {
        float zb = (j == 0) ? zb0 : zb1;
        int lc = j * 4 + hc;
        float act[4];
#pragma unroll
        for (int r = 0; r < 4; ++r) {
          float z = ((j == 0) ? ac0[r] : ac1[r]) + zb;
          act[r] = (g == 2) ? tanhf_(z) : sigmoidf_(z);
        }
#pragma unroll
        for (int r = 0; r < 4; ++r) {
          float fs = __shfl(act[r], base + 1);   // sigmoid(z_f)
          float gt = __shfl(act[r], base + 2);   // tanh(z_g)
          float os = __shfl(act[r], base + 3);   // sigmoid(z_o)
          if (g == 0) {                          // act[r] = sigmoid(z_i)
            int row = w * 16 + ksub * 4 + r;
            bool mm = (mk >> row) & 1ull;
            float cn = fs * cst[j][r] + act[r] * gt;
            float hn = os * tanhf_(cn);
            if (mm) { cst[j][r] = cn; hst[j][r] = hn; }
            hlocF[row][lc] = hst[j][r];
            hlocBF[row][lc] = f2bf(hst[j][r]);
          }
        }
      }
    }
    LGKM0();
    RAW_BAR();   // D: hloc ready

    // --- E: role-split tail ---
    if (w == 4) {
      // publish h (sc1 16B per row), ack h only, then flag
      frag_u v; v.h = *(const bf16x8*)&hlocBF[l][0];
      st_sys(hw + l * H_ + s * 8, v.i);
      VM0();
      if (l == 0) st_sys_i32(flags + s * 16, t + 1);
    } else if (w == 5 || w == 6) {
      // out rows from LDS staging; NEVER wait on these stores
      int p = (w - 5) * 64 + l;
      int row = p >> 1, half = p & 1;
      f32x4 v = *(const f32x4*)&hlocF[row][half * 4];
      __builtin_nontemporal_store(v, (f32x4*)(out + ((size_t)row * T_ + t) * H_ + s * 8 + half * 4));
    } else if (w < 4) {
      if (t == T_ - 1 && g == 0) {
#pragma unroll
        for (int j = 0; j < 2; ++j) {
          int col = s * 8 + j * 4 + hc;
#pragma unroll
          for (int r = 0; r < 4; ++r) {
            int row = w * 16 + ksub * 4 + r;
            out[(size_t)B_ * T_ * H_ + row * H_ + col] = hst[j][r];               // h_T
            out[(size_t)B_ * T_ * H_ + B_ * H_ + row * H_ + col] = cst[j][r];     // c_T
          }
        }
      }
      if (t + 1 < T_) compute_x(t + 1);   // overlaps sync wave's publish
    }
  }
}

// ---------------- launch ----------------

extern "C" void kernel_launch(void* const* d_in, const int* in_sizes, int n_in,
                              void* d_out, int out_size, void* d_ws, size_t ws_size,
                              hipStream_t stream) {
  (void)in_sizes; (void)n_in; (void)out_size; (void)ws_size;
  const int* tokens = (const int*)d_in[0];
  const float* h0 = (const float*)d_in[1];
  const float* c0 = (const float*)d_in[2];
  const float* emb = (const float*)d_in[3];
  const float* Wx = (const float*)d_in[4];
  const float* Wh = (const float*)d_in[5];
  const float* bias = (const float*)d_in[6];
  float* out = (float*)d_out;
  char* ws = (char*)d_ws;

  // ws layout (bytes): emb_bf16 16,384,000 | wfrag 3,145,728 | mask 8,192 |
  //                    tokT 262,144 | hb0 65,536 | hb1 65,536 | flags 4,096
  short* emb_bf = (short*)(ws);
  short* wf     = (short*)(ws + 16384000);
  unsigned long long* mask = (unsigned long long*)(ws + 19529728);
  int* tokT     = (int*)(ws + 19537920);
  short* hb0    = (short*)(ws + 19800064);
  short* hb1    = (short*)(ws + 19865600);
  int* flags    = (int*)(ws + 19931136);

  k_emb_cvt<<<(1024000 + 255) / 256, 256, 0, stream>>>(emb, emb_bf, 1024000);
  k_wfrag<<<(NSLICE * 2 * KT_ * 64 + 255) / 256, 256, 0, stream>>>(Wx, Wh, wf);
  k_tok<<<(T_ + 255) / 256, 256, 0, stream>>>(tokens, tokT, mask);
  k_init<<<(B_ * H_ + 255) / 256, 256, 0, stream>>>(h0, hb0, flags);

  k_lstm<<<NSLICE, 512, 0, stream>>>(tokT, emb_bf, wf, bias, mask,
                                     hb0, hb1, h0, c0, out, flags);
}